// Round 1
// baseline (154.660 us; speedup 1.0000x reference)
//
#include <hip/hip_runtime.h>

// FeaStConv x2, HEADS=1 => softmax over 1 head == 1.0 => attention is identity.
// Layer collapses to relu((segsum(h[src]) @ W)/deg + b). Fuse both GEMMs; never
// materialize the [N,400] hidden. IN=32, HID=400, OUT=4 (read dynamically).

#define TPB 256

__global__ void k_init(const float* __restrict__ x, float* __restrict__ xs,
                       float* __restrict__ deg, int n) {
    int gid = blockIdx.x * blockDim.x + threadIdx.x;  // over n*32
    if (gid < n * 32) {
        xs[gid] = x[gid];                 // self-loop contribution
        if ((gid & 31) == 0) deg[gid >> 5] = 1.0f;  // self-loop degree
    }
}

__global__ void k_scatter_x(const float* __restrict__ x, const int* __restrict__ src,
                            const int* __restrict__ dst, float* __restrict__ xs,
                            float* __restrict__ deg, int E) {
    int gid = blockIdx.x * blockDim.x + threadIdx.x;  // over E*32
    if (gid >= E * 32) return;
    int e = gid >> 5;
    int k = gid & 31;
    int s = src[e];
    int d = dst[e];
    atomicAdd(&xs[d * 32 + k], x[s * 32 + k]);
    if (k == 0) atomicAdd(&deg[d], 1.0f);
}

// Fused: h = relu((xs @ W1)/deg + b1) ; p = h @ W2. Writes p and agg2(=p, the
// self-loop init for the layer-2 aggregation).
__global__ __launch_bounds__(TPB) void k_dense(
    const float* __restrict__ xs, const float* __restrict__ deg,
    const float* __restrict__ W1, const float* __restrict__ b1,
    const float* __restrict__ W2,
    float* __restrict__ p, float* __restrict__ agg2, int n) {
    __shared__ __align__(16) float lW1[32 * 400];
    __shared__ __align__(16) float lW2[400 * 4];
    __shared__ float lb1[400];
    for (int i = threadIdx.x; i < 32 * 400; i += TPB) lW1[i] = W1[i];
    for (int i = threadIdx.x; i < 400 * 4; i += TPB) lW2[i] = W2[i];
    for (int i = threadIdx.x; i < 400; i += TPB) lb1[i] = b1[i];
    __syncthreads();

    int node = blockIdx.x * blockDim.x + threadIdx.x;
    if (node >= n) return;

    float xr[32];
    const float4* xp = (const float4*)(xs + (size_t)node * 32);
#pragma unroll
    for (int q = 0; q < 8; q++) {
        float4 v = xp[q];
        xr[q * 4 + 0] = v.x; xr[q * 4 + 1] = v.y;
        xr[q * 4 + 2] = v.z; xr[q * 4 + 3] = v.w;
    }
    float invd = 1.0f / deg[node];

    float acc0 = 0.f, acc1 = 0.f, acc2 = 0.f, acc3 = 0.f;
    for (int j = 0; j < 400; j += 4) {
        float h0 = 0.f, h1 = 0.f, h2 = 0.f, h3 = 0.f;
#pragma unroll
        for (int k = 0; k < 32; k++) {
            const float4 w = *(const float4*)(&lW1[k * 400 + j]);  // broadcast read
            h0 += xr[k] * w.x; h1 += xr[k] * w.y;
            h2 += xr[k] * w.z; h3 += xr[k] * w.w;
        }
        float hv[4];
        hv[0] = fmaxf(h0 * invd + lb1[j + 0], 0.f);
        hv[1] = fmaxf(h1 * invd + lb1[j + 1], 0.f);
        hv[2] = fmaxf(h2 * invd + lb1[j + 2], 0.f);
        hv[3] = fmaxf(h3 * invd + lb1[j + 3], 0.f);
#pragma unroll
        for (int t = 0; t < 4; t++) {
            const float4 w2 = *(const float4*)(&lW2[(j + t) * 4]);
            acc0 += hv[t] * w2.x; acc1 += hv[t] * w2.y;
            acc2 += hv[t] * w2.z; acc3 += hv[t] * w2.w;
        }
    }
    float4 res = make_float4(acc0, acc1, acc2, acc3);
    *(float4*)(p + (size_t)node * 4) = res;
    *(float4*)(agg2 + (size_t)node * 4) = res;
}

__global__ void k_scatter_p(const float* __restrict__ p, const int* __restrict__ src,
                            const int* __restrict__ dst, float* __restrict__ agg2, int E) {
    int gid = blockIdx.x * blockDim.x + threadIdx.x;  // over E*4
    if (gid >= E * 4) return;
    int e = gid >> 2;
    int c = gid & 3;
    atomicAdd(&agg2[dst[e] * 4 + c], p[src[e] * 4 + c]);
}

__global__ void k_final(const float* __restrict__ agg2, const float* __restrict__ deg,
                        const float* __restrict__ b2, float* __restrict__ out, int n) {
    int gid = blockIdx.x * blockDim.x + threadIdx.x;  // over n*4
    if (gid >= n * 4) return;
    int i = gid >> 2;
    int c = gid & 3;
    out[gid] = fmaxf(agg2[gid] / deg[i] + b2[c], 0.f);
}

extern "C" void kernel_launch(void* const* d_in, const int* in_sizes, int n_in,
                              void* d_out, int out_size, void* d_ws, size_t ws_size,
                              hipStream_t stream) {
    const float* x  = (const float*)d_in[0];
    const int*   ei = (const int*)d_in[1];
    const float* W1 = (const float*)d_in[2];
    // d_in[3] = u1, d_in[4] = c1: dead (softmax over 1 head == 1)
    const float* b1 = (const float*)d_in[5];
    const float* W2 = (const float*)d_in[6];
    // d_in[7] = u2, d_in[8] = c2: dead
    const float* b2 = (const float*)d_in[9];

    int n = in_sizes[0] / 32;
    int E = in_sizes[1] / 2;
    const int* src = ei;
    const int* dst = ei + E;

    float* ws   = (float*)d_ws;
    float* deg  = ws;                        // n
    float* xs   = ws + n;                    // n*32
    float* p    = ws + n + (size_t)n * 32;   // n*4
    float* agg2 = p + (size_t)n * 4;         // n*4
    float* out  = (float*)d_out;

    k_init<<<(n * 32 + TPB - 1) / TPB, TPB, 0, stream>>>(x, xs, deg, n);
    k_scatter_x<<<(E * 32 + TPB - 1) / TPB, TPB, 0, stream>>>(x, src, dst, xs, deg, E);
    k_dense<<<(n + TPB - 1) / TPB, TPB, 0, stream>>>(xs, deg, W1, b1, W2, p, agg2, n);
    k_scatter_p<<<(E * 4 + TPB - 1) / TPB, TPB, 0, stream>>>(p, src, dst, agg2, E);
    k_final<<<(n * 4 + TPB - 1) / TPB, TPB, 0, stream>>>(agg2, deg, b2, out, n);
}

// Round 2
// 113.679 us; speedup vs baseline: 1.3605x; 1.3605x over previous
//
#include <hip/hip_runtime.h>

// FeaStConv x2, HEADS=1 => softmax == 1 => attention identity; layer =
// relu((segsum(h[src]) @ W)/deg + b). Both GEMMs fused per node; hidden [N,400]
// never materialized. Aggregation done as GATHER via per-dst buckets (CAP=16)
// built with one int atomic per edge; overflow edges (rare) fall back to
// float atomics for full correctness.

#define TPB 256
#define CAP 16

__global__ void k_zero(int* __restrict__ cnt, int n1) {
    int gid = blockIdx.x * blockDim.x + threadIdx.x;
    if (gid < n1) cnt[gid] = 0;
}

__global__ void k_fill(const int* __restrict__ src, const int* __restrict__ dst,
                       int* __restrict__ cnt, int* __restrict__ bucket,
                       int* __restrict__ ovf_cnt, int* __restrict__ ovf_list, int E) {
    int e = blockIdx.x * blockDim.x + threadIdx.x;
    if (e >= E) return;
    int d = dst[e];
    int slot = atomicAdd(&cnt[d], 1);
    if (slot < CAP) bucket[d * CAP + slot] = src[e];
    else { int pos = atomicAdd(ovf_cnt, 1); ovf_list[pos] = e; }
}

// one wave per node: lanes 0-31 = channels (even edges), 32-63 = channels (odd edges)
__global__ void k_gather_x(const float* __restrict__ x, const int* __restrict__ cnt,
                           const int* __restrict__ bucket,
                           float* __restrict__ xs, float* __restrict__ deg, int n) {
    int node = blockIdx.x * 4 + (threadIdx.x >> 6);
    if (node >= n) return;
    int lane = threadIdx.x & 63;
    int ch = lane & 31, half = lane >> 5;
    int m = cnt[node];
    int mb = m < CAP ? m : CAP;
    float acc = 0.f;
    for (int i = half; i < mb; i += 2)
        acc += x[(size_t)bucket[node * CAP + i] * 32 + ch];
    acc += __shfl_xor(acc, 32, 64);
    if (half == 0) {
        xs[(size_t)node * 32 + ch] = x[(size_t)node * 32 + ch] + acc;
        if (ch == 0) deg[node] = (float)(m + 1);
    }
}

__global__ void k_fbx(const float* __restrict__ x, const int* __restrict__ src,
                      const int* __restrict__ dst, const int* __restrict__ ovf_cnt,
                      const int* __restrict__ ovf_list, float* __restrict__ xs) {
    int total = ovf_cnt[0] * 32;
    int stride = gridDim.x * blockDim.x;
    for (int idx = blockIdx.x * blockDim.x + threadIdx.x; idx < total; idx += stride) {
        int e = ovf_list[idx >> 5];
        int ch = idx & 31;
        atomicAdd(&xs[(size_t)dst[e] * 32 + ch], x[(size_t)src[e] * 32 + ch]);
    }
}

// 4 threads per node; thread q owns hidden channels [q*100, q*100+100).
__global__ __launch_bounds__(TPB) void k_dense(
    const float* __restrict__ xs, const float* __restrict__ deg,
    const float* __restrict__ W1, const float* __restrict__ b1,
    const float* __restrict__ W2,
    float* __restrict__ p, float* __restrict__ agg2, int n) {
    __shared__ __align__(16) float lW1[32 * 400];
    __shared__ __align__(16) float lW2[400 * 4];
    __shared__ __align__(16) float lb1[400];
    for (int i = threadIdx.x; i < 32 * 400; i += TPB) lW1[i] = W1[i];
    for (int i = threadIdx.x; i < 400 * 4; i += TPB) lW2[i] = W2[i];
    for (int i = threadIdx.x; i < 400; i += TPB) lb1[i] = b1[i];
    __syncthreads();

    int gid = blockIdx.x * TPB + threadIdx.x;
    int node = gid >> 2, q = gid & 3;
    if (node >= n) return;

    float xr[32];
    const float4* xp = (const float4*)(xs + (size_t)node * 32);
#pragma unroll
    for (int t = 0; t < 8; t++) {
        float4 v = xp[t];
        xr[t * 4 + 0] = v.x; xr[t * 4 + 1] = v.y;
        xr[t * 4 + 2] = v.z; xr[t * 4 + 3] = v.w;
    }
    float invd = 1.0f / deg[node];

    float a0 = 0.f, a1 = 0.f, a2 = 0.f, a3 = 0.f;
    int jbase = q * 100;
    for (int jj = 0; jj < 100; jj += 4) {
        int j = jbase + jj;
        float h0 = 0.f, h1 = 0.f, h2 = 0.f, h3 = 0.f;
#pragma unroll
        for (int k = 0; k < 32; k++) {
            const float4 w = *(const float4*)(&lW1[k * 400 + j]);
            h0 = fmaf(xr[k], w.x, h0);
            h1 = fmaf(xr[k], w.y, h1);
            h2 = fmaf(xr[k], w.z, h2);
            h3 = fmaf(xr[k], w.w, h3);
        }
        const float4 bb = *(const float4*)(&lb1[j]);
        float hv0 = fmaxf(fmaf(h0, invd, bb.x), 0.f);
        float hv1 = fmaxf(fmaf(h1, invd, bb.y), 0.f);
        float hv2 = fmaxf(fmaf(h2, invd, bb.z), 0.f);
        float hv3 = fmaxf(fmaf(h3, invd, bb.w), 0.f);
        const float4 w20 = *(const float4*)(&lW2[(j + 0) * 4]);
        const float4 w21 = *(const float4*)(&lW2[(j + 1) * 4]);
        const float4 w22 = *(const float4*)(&lW2[(j + 2) * 4]);
        const float4 w23 = *(const float4*)(&lW2[(j + 3) * 4]);
        a0 = fmaf(hv0, w20.x, a0); a1 = fmaf(hv0, w20.y, a1);
        a2 = fmaf(hv0, w20.z, a2); a3 = fmaf(hv0, w20.w, a3);
        a0 = fmaf(hv1, w21.x, a0); a1 = fmaf(hv1, w21.y, a1);
        a2 = fmaf(hv1, w21.z, a2); a3 = fmaf(hv1, w21.w, a3);
        a0 = fmaf(hv2, w22.x, a0); a1 = fmaf(hv2, w22.y, a1);
        a2 = fmaf(hv2, w22.z, a2); a3 = fmaf(hv2, w22.w, a3);
        a0 = fmaf(hv3, w23.x, a0); a1 = fmaf(hv3, w23.y, a1);
        a2 = fmaf(hv3, w23.z, a2); a3 = fmaf(hv3, w23.w, a3);
    }
    a0 += __shfl_xor(a0, 1); a0 += __shfl_xor(a0, 2);
    a1 += __shfl_xor(a1, 1); a1 += __shfl_xor(a1, 2);
    a2 += __shfl_xor(a2, 1); a2 += __shfl_xor(a2, 2);
    a3 += __shfl_xor(a3, 1); a3 += __shfl_xor(a3, 2);
    if (q == 0) {
        float4 r = make_float4(a0, a1, a2, a3);
        *(float4*)(p + (size_t)node * 4) = r;
        *(float4*)(agg2 + (size_t)node * 4) = r;
    }
}

__global__ void k_gather_p(const float* __restrict__ p, const int* __restrict__ cnt,
                           const int* __restrict__ bucket, float* __restrict__ agg2, int n) {
    int gid = blockIdx.x * blockDim.x + threadIdx.x;
    int node = gid >> 2, c = gid & 3;
    if (node >= n) return;
    int m = cnt[node];
    int mb = m < CAP ? m : CAP;
    float acc = p[(size_t)node * 4 + c];
    for (int i = 0; i < mb; i++)
        acc += p[(size_t)bucket[node * CAP + i] * 4 + c];
    agg2[gid] = acc;
}

__global__ void k_fbp(const float* __restrict__ p, const int* __restrict__ src,
                      const int* __restrict__ dst, const int* __restrict__ ovf_cnt,
                      const int* __restrict__ ovf_list, float* __restrict__ agg2) {
    int total = ovf_cnt[0] * 4;
    int stride = gridDim.x * blockDim.x;
    for (int idx = blockIdx.x * blockDim.x + threadIdx.x; idx < total; idx += stride) {
        int e = ovf_list[idx >> 2];
        int c = idx & 3;
        atomicAdd(&agg2[(size_t)dst[e] * 4 + c], p[(size_t)src[e] * 4 + c]);
    }
}

__global__ void k_final(const float* __restrict__ agg2, const float* __restrict__ deg,
                        const float* __restrict__ b2, float* __restrict__ out, int n) {
    int gid = blockIdx.x * blockDim.x + threadIdx.x;
    if (gid >= n * 4) return;
    int i = gid >> 2;
    int c = gid & 3;
    out[gid] = fmaxf(agg2[gid] / deg[i] + b2[c], 0.f);
}

extern "C" void kernel_launch(void* const* d_in, const int* in_sizes, int n_in,
                              void* d_out, int out_size, void* d_ws, size_t ws_size,
                              hipStream_t stream) {
    const float* x  = (const float*)d_in[0];
    const int*   ei = (const int*)d_in[1];
    const float* W1 = (const float*)d_in[2];
    const float* b1 = (const float*)d_in[5];
    const float* W2 = (const float*)d_in[6];
    const float* b2 = (const float*)d_in[9];

    int n = in_sizes[0] / 32;
    int E = in_sizes[1] / 2;
    const int* src = ei;
    const int* dst = ei + E;

    // workspace layout
    int*   cnt      = (int*)d_ws;                 // n
    int*   ovf_cnt  = cnt + n;                    // 1
    int*   ovf_list = ovf_cnt + 1;                // E
    int*   bucket   = ovf_list + E;               // n*CAP
    float* xs       = (float*)(bucket + (size_t)n * CAP);  // n*32
    float* deg      = xs + (size_t)n * 32;        // n
    float* p        = deg + n;                    // n*4
    float* agg2     = p + (size_t)n * 4;          // n*4
    float* out      = (float*)d_out;

    k_zero<<<(n + 1 + TPB - 1) / TPB, TPB, 0, stream>>>(cnt, n + 1);
    k_fill<<<(E + TPB - 1) / TPB, TPB, 0, stream>>>(src, dst, cnt, bucket,
                                                    ovf_cnt, ovf_list, E);
    k_gather_x<<<(n + 3) / 4, TPB, 0, stream>>>(x, cnt, bucket, xs, deg, n);
    k_fbx<<<128, TPB, 0, stream>>>(x, src, dst, ovf_cnt, ovf_list, xs);
    k_dense<<<(n * 4 + TPB - 1) / TPB, TPB, 0, stream>>>(xs, deg, W1, b1, W2, p, agg2, n);
    k_gather_p<<<(n * 4 + TPB - 1) / TPB, TPB, 0, stream>>>(p, cnt, bucket, agg2, n);
    k_fbp<<<64, TPB, 0, stream>>>(p, src, dst, ovf_cnt, ovf_list, agg2);
    k_final<<<(n * 4 + TPB - 1) / TPB, TPB, 0, stream>>>(agg2, deg, b2, out, n);
}

// Round 3
// 80.125 us; speedup vs baseline: 1.9302x; 1.4188x over previous
//
#include <hip/hip_runtime.h>

// FeaStConv x2, HEADS=1 => softmax==1 => layer = relu((segsum(h[src])@W)/deg + b).
// Gather via per-dst buckets (CAP=16, atomic-append; overflow fallback kernels).
// Dense part: xs[N,32]@W1[32,400] via mfma_f32_16x16x32_bf16 with 3-term
// hi/lo bf16 split (error ~2^-16), fused relu/scale + @W2[400,4] epilogue.

#define TPB 256
#define CAP 16

typedef __attribute__((ext_vector_type(8))) short bf16x8;
typedef __attribute__((ext_vector_type(4))) float f32x4;

__device__ __forceinline__ void split_bf16(float f, ushort& hi, ushort& lo) {
    unsigned u = __float_as_uint(f);
    unsigned h = u >> 16;
    float fh = __uint_as_float(h << 16);
    float r = f - fh;                      // exact
    hi = (ushort)h;
    lo = (ushort)(__float_as_uint(r) >> 16);
}

// blocks [0,nfb): bucket fill. blocks [nfb, nfb+7): W1 fragment repack.
__global__ void k_fill_prep(const int* __restrict__ src, const int* __restrict__ dst,
                            int* __restrict__ cnt, int* __restrict__ bucket,
                            int* __restrict__ ovf_cnt, int* __restrict__ ovf_list,
                            int E, int nfb, const float* __restrict__ W1,
                            ushort* __restrict__ packHi, ushort* __restrict__ packLo) {
    if ((int)blockIdx.x < nfb) {
        int e = blockIdx.x * TPB + threadIdx.x;
        if (e >= E) return;
        int d = dst[e];
        int slot = atomicAdd(&cnt[d], 1);
        if (slot < CAP) bucket[d * CAP + slot] = src[e];
        else { int pos = atomicAdd(ovf_cnt, 1); ovf_list[pos] = e; }
    } else {
        int t = (blockIdx.x - nfb) * TPB + threadIdx.x;   // 25*64 = 1600 frags
        if (t >= 25 * 64) return;
        int ct = t >> 6, l = t & 63;
        int kh = l >> 4, c = l & 15;
#pragma unroll
        for (int e = 0; e < 8; e++) {
            // B[k][col] fragment: k = 8*kh + e, col = ct*16 + c
            float f = W1[(8 * kh + e) * 400 + ct * 16 + c];
            ushort h, lo; split_bf16(f, h, lo);
            packHi[t * 8 + e] = h;
            packLo[t * 8 + e] = lo;
        }
    }
}

// one wave per node; lanes = 32 ch x 2 halves; predicated unrolled gather.
__global__ void k_gather_x(const float* __restrict__ x, const int* __restrict__ cnt,
                           const int* __restrict__ bucket,
                           float* __restrict__ xs, float* __restrict__ invd, int n) {
    int node = blockIdx.x * 4 + (threadIdx.x >> 6);
    if (node >= n) return;
    int lane = threadIdx.x & 63;
    int ch = lane & 31, h = lane >> 5;
    int m = cnt[node];
    int mb = m < CAP ? m : CAP;
    float acc = 0.f;
    const int4* bkt = (const int4*)(bucket + (size_t)node * CAP);
#pragma unroll
    for (int c = 0; c < 2; c++) {                 // chunk = slots 8c..8c+7
        if (8 * c < mb) {                          // wave-uniform branch
            int4 b = bkt[2 * c + h];               // slots 8c+4h .. 8c+4h+3
            int s0 = 8 * c + 4 * h;
            int i0 = (s0 + 0 < mb) ? b.x : node;
            int i1 = (s0 + 1 < mb) ? b.y : node;
            int i2 = (s0 + 2 < mb) ? b.z : node;
            int i3 = (s0 + 3 < mb) ? b.w : node;
            float v0 = x[(size_t)i0 * 32 + ch];
            float v1 = x[(size_t)i1 * 32 + ch];
            float v2 = x[(size_t)i2 * 32 + ch];
            float v3 = x[(size_t)i3 * 32 + ch];
            acc += (s0 + 0 < mb) ? v0 : 0.f;
            acc += (s0 + 1 < mb) ? v1 : 0.f;
            acc += (s0 + 2 < mb) ? v2 : 0.f;
            acc += (s0 + 3 < mb) ? v3 : 0.f;
        }
    }
    acc += __shfl_xor(acc, 32, 64);
    if (h == 0) {
        xs[(size_t)node * 32 + ch] = x[(size_t)node * 32 + ch] + acc;
        if (ch == 0) invd[node] = 1.0f / (float)(m + 1);
    }
}

__global__ void k_fbx(const float* __restrict__ x, const int* __restrict__ src,
                      const int* __restrict__ dst, const int* __restrict__ ovf_cnt,
                      const int* __restrict__ ovf_list, float* __restrict__ xs) {
    int total = ovf_cnt[0] * 32;
    int stride = gridDim.x * blockDim.x;
    for (int idx = blockIdx.x * blockDim.x + threadIdx.x; idx < total; idx += stride) {
        int e = ovf_list[idx >> 5];
        int ch = idx & 31;
        atomicAdd(&xs[(size_t)dst[e] * 32 + ch], x[(size_t)src[e] * 32 + ch]);
    }
}

// MFMA dense: 4 waves/block, each wave = 16 nodes, full 400 hidden channels.
__global__ __launch_bounds__(256) void k_dense(
    const float* __restrict__ xs, const float* __restrict__ invd,
    const ushort* __restrict__ packHi, const ushort* __restrict__ packLo,
    const float* __restrict__ b1, const float* __restrict__ W2,
    float* __restrict__ p, int n) {
    __shared__ float lb1[400];
    __shared__ __align__(16) float lW2[1600];
    for (int i = threadIdx.x; i < 400; i += 256) lb1[i] = b1[i];
    for (int i = threadIdx.x; i < 1600; i += 256) lW2[i] = W2[i];
    __syncthreads();

    int wid = threadIdx.x >> 6, l = threadIdx.x & 63;
    int base_w = blockIdx.x * 64 + wid * 16;
    int r = l & 15, kh = l >> 4;

    // A fragment: lane holds xs[base_w + r][kh*8 .. kh*8+7], hi/lo split
    int nr = base_w + r; if (nr > n - 1) nr = n - 1;
    const float4* xp = (const float4*)(xs + (size_t)nr * 32 + kh * 8);
    float4 v0 = xp[0], v1 = xp[1];
    float xv[8] = {v0.x, v0.y, v0.z, v0.w, v1.x, v1.y, v1.z, v1.w};
    bf16x8 a_hi, a_lo;
#pragma unroll
    for (int e = 0; e < 8; e++) {
        ushort h, lo; split_bf16(xv[e], h, lo);
        a_hi[e] = (short)h; a_lo[e] = (short)lo;
    }

    float invd_q[4];
#pragma unroll
    for (int q = 0; q < 4; q++) {
        int idx = base_w + kh * 4 + q; if (idx > n - 1) idx = n - 1;
        invd_q[q] = invd[idx];
    }

    float pacc[4][4];
#pragma unroll
    for (int q = 0; q < 4; q++)
#pragma unroll
        for (int o = 0; o < 4; o++) pacc[q][o] = 0.f;

    for (int ct = 0; ct < 25; ct++) {
        bf16x8 bh = *(const bf16x8*)(packHi + ((size_t)ct * 64 + l) * 8);
        bf16x8 bl = *(const bf16x8*)(packLo + ((size_t)ct * 64 + l) * 8);
        f32x4 acc = {0.f, 0.f, 0.f, 0.f};
        acc = __builtin_amdgcn_mfma_f32_16x16x32_bf16(a_hi, bh, acc, 0, 0, 0);
        acc = __builtin_amdgcn_mfma_f32_16x16x32_bf16(a_lo, bh, acc, 0, 0, 0);
        acc = __builtin_amdgcn_mfma_f32_16x16x32_bf16(a_hi, bl, acc, 0, 0, 0);
        float b1v = lb1[ct * 16 + r];
        const float4 w2v = *(const float4*)(&lW2[(ct * 16 + r) * 4]);
#pragma unroll
        for (int q = 0; q < 4; q++) {
            float h = fmaxf(fmaf(acc[q], invd_q[q], b1v), 0.f);
            pacc[q][0] = fmaf(h, w2v.x, pacc[q][0]);
            pacc[q][1] = fmaf(h, w2v.y, pacc[q][1]);
            pacc[q][2] = fmaf(h, w2v.z, pacc[q][2]);
            pacc[q][3] = fmaf(h, w2v.w, pacc[q][3]);
        }
    }
    // reduce over the 16 lanes (xor bits 0..3 keeps the kh group)
#pragma unroll
    for (int mask = 1; mask <= 8; mask <<= 1)
#pragma unroll
        for (int q = 0; q < 4; q++)
#pragma unroll
            for (int o = 0; o < 4; o++)
                pacc[q][o] += __shfl_xor(pacc[q][o], mask, 64);

    if (r < 4) {
        int node = base_w + kh * 4 + r;
        if (node < n)
            *(float4*)(p + (size_t)node * 4) =
                make_float4(pacc[r][0], pacc[r][1], pacc[r][2], pacc[r][3]);
    }
}

__global__ void k_gather_p(const float* __restrict__ p, const int* __restrict__ cnt,
                           const int* __restrict__ bucket, float* __restrict__ agg2, int n) {
    int gid = blockIdx.x * blockDim.x + threadIdx.x;
    int node = gid >> 2, c = gid & 3;
    if (node >= n) return;
    int m = cnt[node];
    int mb = m < CAP ? m : CAP;
    float acc = p[(size_t)node * 4 + c];
    const int4* bkt = (const int4*)(bucket + (size_t)node * CAP);
#pragma unroll
    for (int c4 = 0; c4 < 4; c4++) {
        if (4 * c4 < mb) {
            int4 b = bkt[c4];
            int s0 = 4 * c4;
            int i0 = (s0 + 0 < mb) ? b.x : node;
            int i1 = (s0 + 1 < mb) ? b.y : node;
            int i2 = (s0 + 2 < mb) ? b.z : node;
            int i3 = (s0 + 3 < mb) ? b.w : node;
            float v0 = p[(size_t)i0 * 4 + c];
            float v1 = p[(size_t)i1 * 4 + c];
            float v2 = p[(size_t)i2 * 4 + c];
            float v3 = p[(size_t)i3 * 4 + c];
            acc += (s0 + 0 < mb) ? v0 : 0.f;
            acc += (s0 + 1 < mb) ? v1 : 0.f;
            acc += (s0 + 2 < mb) ? v2 : 0.f;
            acc += (s0 + 3 < mb) ? v3 : 0.f;
        }
    }
    agg2[gid] = acc;
}

__global__ void k_fbp(const float* __restrict__ p, const int* __restrict__ src,
                      const int* __restrict__ dst, const int* __restrict__ ovf_cnt,
                      const int* __restrict__ ovf_list, float* __restrict__ agg2) {
    int total = ovf_cnt[0] * 4;
    int stride = gridDim.x * blockDim.x;
    for (int idx = blockIdx.x * blockDim.x + threadIdx.x; idx < total; idx += stride) {
        int e = ovf_list[idx >> 2];
        int c = idx & 3;
        atomicAdd(&agg2[(size_t)dst[e] * 4 + c], p[(size_t)src[e] * 4 + c]);
    }
}

__global__ void k_final(const float* __restrict__ agg2, const float* __restrict__ invd,
                        const float* __restrict__ b2, float* __restrict__ out, int n) {
    int gid = blockIdx.x * blockDim.x + threadIdx.x;
    if (gid >= n * 4) return;
    int i = gid >> 2;
    int c = gid & 3;
    out[gid] = fmaxf(fmaf(agg2[gid], invd[i], b2[c]), 0.f);
}

static inline size_t align4i(size_t v) { return (v + 3) & ~(size_t)3; }

extern "C" void kernel_launch(void* const* d_in, const int* in_sizes, int n_in,
                              void* d_out, int out_size, void* d_ws, size_t ws_size,
                              hipStream_t stream) {
    const float* x  = (const float*)d_in[0];
    const int*   ei = (const int*)d_in[1];
    const float* W1 = (const float*)d_in[2];
    const float* b1 = (const float*)d_in[5];
    const float* W2 = (const float*)d_in[6];
    const float* b2 = (const float*)d_in[9];

    int n = in_sizes[0] / 32;
    int E = in_sizes[1] / 2;
    const int* src = ei;
    const int* dst = ei + E;

    // workspace layout (int units, 16B-aligned sections)
    int* wsi = (int*)d_ws;
    size_t off = 0;
    int* cnt      = wsi + off; off += n;                 // n
    int* ovf_cnt  = wsi + off; off += 1;                 // 1 (memset with cnt)
    size_t off_ovf = align4i(off);
    int* ovf_list = wsi + off_ovf; off = off_ovf + E;
    size_t off_b  = align4i(off);
    int* bucket   = wsi + off_b;  off = off_b + (size_t)n * CAP;
    size_t off_f  = align4i(off);
    float* xs     = (float*)(wsi + off_f); off = off_f + (size_t)n * 32;
    float* invd   = (float*)(wsi + off);   off += n;
    size_t off_p  = align4i(off);
    float* p      = (float*)(wsi + off_p); off = off_p + (size_t)n * 4;
    float* agg2   = (float*)(wsi + off);   off += (size_t)n * 4;
    size_t off_ph = align4i(off);
    ushort* packHi = (ushort*)(wsi + off_ph); off = off_ph + 25 * 64 * 8 / 2;
    ushort* packLo = (ushort*)(wsi + off);
    float* out    = (float*)d_out;

    hipMemsetAsync(cnt, 0, (size_t)(n + 1) * sizeof(int), stream);
    int nfb = (E + TPB - 1) / TPB;
    k_fill_prep<<<nfb + 7, TPB, 0, stream>>>(src, dst, cnt, bucket, ovf_cnt,
                                             ovf_list, E, nfb, W1, packHi, packLo);
    k_gather_x<<<(n + 3) / 4, TPB, 0, stream>>>(x, cnt, bucket, xs, invd, n);
    k_fbx<<<128, TPB, 0, stream>>>(x, src, dst, ovf_cnt, ovf_list, xs);
    k_dense<<<(n + 63) / 64, 256, 0, stream>>>(xs, invd, packHi, packLo, b1, W2, p, n);
    k_gather_p<<<((size_t)n * 4 + TPB - 1) / TPB, TPB, 0, stream>>>(p, cnt, bucket, agg2, n);
    k_fbp<<<64, TPB, 0, stream>>>(p, src, dst, ovf_cnt, ovf_list, agg2);
    k_final<<<((size_t)n * 4 + TPB - 1) / TPB, TPB, 0, stream>>>(agg2, invd, b2, out, n);
}

// Round 4
// 71.408 us; speedup vs baseline: 2.1659x; 1.1221x over previous
//
#include <hip/hip_runtime.h>

// FeaStConv x2, HEADS=1 => softmax==1 => layer = relu((segsum(h[src])@W)/deg + b).
// 4-kernel pipeline:
//   k_prep   : zero cnt + repack W1 into per-lane MFMA B-fragments (hi/lo bf16)
//   k_fill   : per-dst bucket build (CAP=32, atomic append; overflow -> (src,dst) list)
//   k_gdense : FUSED neighbor-gather (straight into A-fragments) + 3-term bf16-split
//              MFMA (xs@W1) + relu/deg/b1 + W2 epilogue -> p[N,4]
//   k_out    : layer-2 gather of p + bias/relu -> out
// Overflow (deg>CAP) handled by in-kernel scan of the tiny overflow list.

#define TPB 256
#define CAP 32

typedef __attribute__((ext_vector_type(8))) short bf16x8;
typedef __attribute__((ext_vector_type(4))) float f32x4;

__device__ __forceinline__ void split_bf16(float f, ushort& hi, ushort& lo) {
    unsigned u = __float_as_uint(f);
    unsigned h = u >> 16;
    float fh = __uint_as_float(h << 16);
    float r = f - fh;                      // exact
    hi = (ushort)h;
    lo = (ushort)(__float_as_uint(r) >> 16);
}

// blocks [0, zb): zero cnt (+ovf_cnt). blocks [zb, zb+7): W1 fragment repack.
__global__ void k_prep(int* __restrict__ cnt, int n1, int zb,
                       const float* __restrict__ W1,
                       ushort* __restrict__ packHi, ushort* __restrict__ packLo) {
    if ((int)blockIdx.x < zb) {
        int gid = blockIdx.x * TPB + threadIdx.x;
        if (gid < n1) cnt[gid] = 0;
    } else {
        int t = (blockIdx.x - zb) * TPB + threadIdx.x;   // 25*64 = 1600 frags
        if (t >= 25 * 64) return;
        int ct = t >> 6, l = t & 63;
        int kh = l >> 4, c = l & 15;
#pragma unroll
        for (int e = 0; e < 8; e++) {
            // B[k][col] fragment: k = 8*kh + e, col = ct*16 + c
            float f = W1[(8 * kh + e) * 400 + ct * 16 + c];
            ushort h, lo; split_bf16(f, h, lo);
            packHi[t * 8 + e] = h;
            packLo[t * 8 + e] = lo;
        }
    }
}

__global__ void k_fill(const int* __restrict__ src, const int* __restrict__ dst,
                       int* __restrict__ cnt, int* __restrict__ bucket,
                       int* __restrict__ ovf_cnt, int2* __restrict__ ovf_list, int E) {
    int e = blockIdx.x * TPB + threadIdx.x;
    if (e >= E) return;
    int d = dst[e];
    int s = src[e];
    int slot = atomicAdd(&cnt[d], 1);
    if (slot < CAP) bucket[(size_t)d * CAP + slot] = s;
    else { int pos = atomicAdd(ovf_cnt, 1); ovf_list[pos] = make_int2(s, d); }
}

// 4 waves/block, wave = 16 nodes. Lane l: node r = l&15, channel octet kh = l>>4.
// Gather neighbor sums directly into A-fragment registers, then MFMA.
__global__ __launch_bounds__(256) void k_gdense(
    const float* __restrict__ x, const int* __restrict__ cnt,
    const int* __restrict__ bucket, const int* __restrict__ ovf_cnt,
    const int2* __restrict__ ovf_list,
    const ushort* __restrict__ packHi, const ushort* __restrict__ packLo,
    const float* __restrict__ b1, const float* __restrict__ W2,
    float* __restrict__ p, int n) {
    __shared__ float lb1[400];
    __shared__ __align__(16) float lW2[1600];
    for (int i = threadIdx.x; i < 400; i += 256) lb1[i] = b1[i];
    for (int i = threadIdx.x; i < 1600; i += 256) lW2[i] = W2[i];

    int wid = threadIdx.x >> 6, l = threadIdx.x & 63;
    int base_w = blockIdx.x * 64 + wid * 16;
    int r = l & 15, kh = l >> 4;

    int node = base_w + r; if (node > n - 1) node = n - 1;
    int m = cnt[node];
    int mb = m < CAP ? m : CAP;

    // self term
    const float4* xp = (const float4*)(x + (size_t)node * 32 + kh * 8);
    float4 s0 = xp[0], s1 = xp[1];
    float acc[8] = {s0.x, s0.y, s0.z, s0.w, s1.x, s1.y, s1.z, s1.w};

    const int4* bkt = (const int4*)(bucket + (size_t)node * CAP);
#pragma unroll
    for (int c4 = 0; c4 < CAP / 4; c4++) {
        if (4 * c4 < mb) {
            int4 b = bkt[c4];
            int base_s = 4 * c4;
            int ids[4] = {b.x, b.y, b.z, b.w};
#pragma unroll
            for (int j = 0; j < 4; j++) {
                if (base_s + j < mb) {
                    const float4* vp = (const float4*)(x + (size_t)ids[j] * 32 + kh * 8);
                    float4 v0 = vp[0], v1 = vp[1];
                    acc[0] += v0.x; acc[1] += v0.y; acc[2] += v0.z; acc[3] += v0.w;
                    acc[4] += v1.x; acc[5] += v1.y; acc[6] += v1.z; acc[7] += v1.w;
                }
            }
        }
    }
    if (m > CAP) {                      // ~never taken; exec-masked
        int L = ovf_cnt[0];
        for (int j = 0; j < L; j++) {
            int2 sd = ovf_list[j];
            if (sd.y == node) {
                const float4* vp = (const float4*)(x + (size_t)sd.x * 32 + kh * 8);
                float4 v0 = vp[0], v1 = vp[1];
                acc[0] += v0.x; acc[1] += v0.y; acc[2] += v0.z; acc[3] += v0.w;
                acc[4] += v1.x; acc[5] += v1.y; acc[6] += v1.z; acc[7] += v1.w;
            }
        }
    }

    bf16x8 a_hi, a_lo;
#pragma unroll
    for (int e = 0; e < 8; e++) {
        ushort h, lo; split_bf16(acc[e], h, lo);
        a_hi[e] = (short)h; a_lo[e] = (short)lo;
    }

    float invd_q[4];
#pragma unroll
    for (int q = 0; q < 4; q++) {
        int nq = base_w + kh * 4 + q; if (nq > n - 1) nq = n - 1;
        invd_q[q] = 1.0f / (float)(cnt[nq] + 1);
    }

    __syncthreads();   // lb1/lW2 ready (loads issued at top)

    float pacc[4][4];
#pragma unroll
    for (int q = 0; q < 4; q++)
#pragma unroll
        for (int o = 0; o < 4; o++) pacc[q][o] = 0.f;

    for (int ct = 0; ct < 25; ct++) {
        bf16x8 bh = *(const bf16x8*)(packHi + ((size_t)ct * 64 + l) * 8);
        bf16x8 bl = *(const bf16x8*)(packLo + ((size_t)ct * 64 + l) * 8);
        f32x4 c = {0.f, 0.f, 0.f, 0.f};
        c = __builtin_amdgcn_mfma_f32_16x16x32_bf16(a_hi, bh, c, 0, 0, 0);
        c = __builtin_amdgcn_mfma_f32_16x16x32_bf16(a_lo, bh, c, 0, 0, 0);
        c = __builtin_amdgcn_mfma_f32_16x16x32_bf16(a_hi, bl, c, 0, 0, 0);
        float b1v = lb1[ct * 16 + r];
        const float4 w2v = *(const float4*)(&lW2[(ct * 16 + r) * 4]);
#pragma unroll
        for (int q = 0; q < 4; q++) {
            float h = fmaxf(fmaf(c[q], invd_q[q], b1v), 0.f);
            pacc[q][0] = fmaf(h, w2v.x, pacc[q][0]);
            pacc[q][1] = fmaf(h, w2v.y, pacc[q][1]);
            pacc[q][2] = fmaf(h, w2v.z, pacc[q][2]);
            pacc[q][3] = fmaf(h, w2v.w, pacc[q][3]);
        }
    }
#pragma unroll
    for (int mask = 1; mask <= 8; mask <<= 1)
#pragma unroll
        for (int q = 0; q < 4; q++)
#pragma unroll
            for (int o = 0; o < 4; o++)
                pacc[q][o] += __shfl_xor(pacc[q][o], mask, 64);

    if (r < 4) {
        int nd = base_w + kh * 4 + r;
        if (nd < n)
            *(float4*)(p + (size_t)nd * 4) =
                make_float4(pacc[r][0], pacc[r][1], pacc[r][2], pacc[r][3]);
    }
}

// layer-2: agg = p[node] + sum_nb p[nb]; out = relu(agg/deg + b2). 1 thread per (node,c).
__global__ void k_out(const float* __restrict__ p, const int* __restrict__ cnt,
                      const int* __restrict__ bucket, const int* __restrict__ ovf_cnt,
                      const int2* __restrict__ ovf_list,
                      const float* __restrict__ b2, float* __restrict__ out, int n) {
    int gid = blockIdx.x * blockDim.x + threadIdx.x;
    int node = gid >> 2, c = gid & 3;
    if (node >= n) return;
    int m = cnt[node];
    int mb = m < CAP ? m : CAP;
    float acc = p[(size_t)node * 4 + c];
    const int4* bkt = (const int4*)(bucket + (size_t)node * CAP);
#pragma unroll
    for (int c4 = 0; c4 < CAP / 4; c4++) {
        if (4 * c4 < mb) {
            int4 b = bkt[c4];
            int base_s = 4 * c4;
            int ids[4] = {b.x, b.y, b.z, b.w};
#pragma unroll
            for (int j = 0; j < 4; j++) {
                if (base_s + j < mb) acc += p[(size_t)ids[j] * 4 + c];
            }
        }
    }
    if (m > CAP) {
        int L = ovf_cnt[0];
        for (int j = 0; j < L; j++) {
            int2 sd = ovf_list[j];
            if (sd.y == node) acc += p[(size_t)sd.x * 4 + c];
        }
    }
    out[gid] = fmaxf(fmaf(acc, 1.0f / (float)(m + 1), b2[c]), 0.f);
}

static inline size_t align4i(size_t v) { return (v + 3) & ~(size_t)3; }

extern "C" void kernel_launch(void* const* d_in, const int* in_sizes, int n_in,
                              void* d_out, int out_size, void* d_ws, size_t ws_size,
                              hipStream_t stream) {
    const float* x  = (const float*)d_in[0];
    const int*   ei = (const int*)d_in[1];
    const float* W1 = (const float*)d_in[2];
    const float* b1 = (const float*)d_in[5];
    const float* W2 = (const float*)d_in[6];
    const float* b2 = (const float*)d_in[9];

    int n = in_sizes[0] / 32;
    int E = in_sizes[1] / 2;
    const int* src = ei;
    const int* dst = ei + E;

    // workspace layout (int units, 16B-aligned sections)
    int* wsi = (int*)d_ws;
    size_t off = 0;
    int* cnt      = wsi + off; off += n;                 // n
    int* ovf_cnt  = wsi + off; off += 1;                 // zeroed together with cnt
    size_t off_ovf = align4i(off);
    int2* ovf_list = (int2*)(wsi + off_ovf); off = off_ovf + 2 * (size_t)E;
    size_t off_b  = align4i(off);
    int* bucket   = wsi + off_b;  off = off_b + (size_t)n * CAP;
    size_t off_p  = align4i(off);
    float* p      = (float*)(wsi + off_p); off = off_p + (size_t)n * 4;
    size_t off_ph = align4i(off);
    ushort* packHi = (ushort*)(wsi + off_ph); off = off_ph + 25 * 64 * 8 / 2;
    ushort* packLo = (ushort*)(wsi + off);
    float* out    = (float*)d_out;

    int zb = (n + 1 + TPB - 1) / TPB;
    k_prep<<<zb + 7, TPB, 0, stream>>>(cnt, n + 1, zb, W1, packHi, packLo);
    k_fill<<<(E + TPB - 1) / TPB, TPB, 0, stream>>>(src, dst, cnt, bucket,
                                                    ovf_cnt, ovf_list, E);
    k_gdense<<<(n + 63) / 64, 256, 0, stream>>>(x, cnt, bucket, ovf_cnt, ovf_list,
                                                packHi, packLo, b1, W2, p, n);
    k_out<<<((size_t)n * 4 + TPB - 1) / TPB, TPB, 0, stream>>>(p, cnt, bucket,
                                                               ovf_cnt, ovf_list,
                                                               b2, out, n);
}